// Round 15
// baseline (197.653 us; speedup 1.0000x reference)
//
#include <hip/hip_runtime.h>
#include <hip/hip_bf16.h>

#define HW 16384
#define DIM 192
#define DIM2 384
#define NB 8
#define HEADS 8
#define CD 24
#define NSPLIT 128

typedef float f32x4 __attribute__((ext_vector_type(4)));
typedef short bf16x8 __attribute__((ext_vector_type(8)));
typedef short s16x4 __attribute__((ext_vector_type(4)));

__device__ __forceinline__ short f2bf(float f) {
    __hip_bfloat16 h = __float2bfloat16(f);
    return *reinterpret_cast<short*>(&h);
}
__device__ __forceinline__ float bf2f(short s) {
    __hip_bfloat16 h = *reinterpret_cast<__hip_bfloat16*>(&s);
    return __bfloat162float(h);
}

// ---------------------------------------------------------------------------
// prep: w1 (384x192 f32) -> bf16 packed in MFMA-fragment order
// ---------------------------------------------------------------------------
__global__ __launch_bounds__(256)
void prep_w1(const float* __restrict__ w1, short* __restrict__ wb1)
{
    int idx = blockIdx.x * 256 + threadIdx.x;      // < 24*6*64 = 9216
    if (idx >= 9216) return;
    int mi = idx / 384, rem = idx % 384;
    int c = rem >> 6, l = rem & 63;
    int oc = mi * 16 + (l & 15);
    int kb = c * 32 + (l >> 4) * 8;
    const float* src = w1 + (long)oc * DIM + kb;
    float4 v0 = *reinterpret_cast<const float4*>(src);
    float4 v1 = *reinterpret_cast<const float4*>(src + 4);
    bf16x8 o;
    o[0]=f2bf(v0.x); o[1]=f2bf(v0.y); o[2]=f2bf(v0.z); o[3]=f2bf(v0.w);
    o[4]=f2bf(v1.x); o[5]=f2bf(v1.y); o[6]=f2bf(v1.z); o[7]=f2bf(v1.w);
    *reinterpret_cast<bf16x8*>(wb1 + (long)idx * 8) = o;
}

// ---------------------------------------------------------------------------
// MFMA GEMM, K=192 (r9 structure, proven best): block = TWO 128-px slabs,
// slab-level software pipeline. Full-line epilogue store segments.
// ---------------------------------------------------------------------------
template<int NOCT, bool B_F32, bool PER_BATCH_A, bool OUT_F32>
__global__ __launch_bounds__(256, 2)
void gemm_k192(const short* __restrict__ Ab, const void* __restrict__ Bg,
               void* __restrict__ Cg, long bstrideB, long bstrideC)
{
    __shared__ short lds[128 * 200];     // B slab (51.2 KB)
    __shared__ float eps[4][16 * 36];    // epilogue transpose buf (9 KB)
    const int tid  = threadIdx.x;
    const int lane = tid & 63;
    const int wave = tid >> 6;
    const int pxbase = blockIdx.x * 256; // two 128-px slabs per block
    const int b    = blockIdx.y;

    const int row  = lane & 15;
    const int kgrp = lane >> 4;          // 0..3
    const short* A0 = Ab + (PER_BATCH_A ? (long)b * NOCT * 3072 : 0);

    bf16x8 aA[6], aB[6];
    auto loadA = [&](bf16x8* dst, int mi) {
#pragma unroll
        for (int c = 0; c < 6; c++)
            dst[c] = *reinterpret_cast<const bf16x8*>(
                &A0[((long)(mi * 6 + c) * 64 + lane) * 8]);
    };

    // ---- staging: thread (q = px-quad 0..31, kl = k-lane 0..7) ----
    const int q  = tid & 31;             // px = 4q .. 4q+3
    const int kl = tid >> 5;             // k = 32j + 4kl + e
    f32x4 stf[6][4];
    s16x4 sth[6][4];
    auto SLOAD = [&](int px0) {          // issue 24 vector loads (kept in regs)
        if constexpr (B_F32) {
            const float* src = (const float*)Bg + (long)b * bstrideB + px0 + q * 4;
#pragma unroll
            for (int j = 0; j < 6; j++)
#pragma unroll
                for (int e = 0; e < 4; e++)
                    stf[j][e] = __builtin_nontemporal_load(
                        reinterpret_cast<const f32x4*>(src + (long)(32 * j + 4 * kl + e) * HW));
        } else {
            const short* src = (const short*)Bg + (long)b * bstrideB + px0 + q * 4;
#pragma unroll
            for (int j = 0; j < 6; j++)
#pragma unroll
                for (int e = 0; e < 4; e++)
                    sth[j][e] = __builtin_nontemporal_load(
                        reinterpret_cast<const s16x4*>(src + (long)(32 * j + 4 * kl + e) * HW));
        }
    };
    auto SWRITE = [&]() {                // cvt + transpose + swizzled LDS write
        const int goff = (((kl >> 1) ^ (q & 3)) << 3) + (kl & 1) * 4;
#pragma unroll
        for (int j = 0; j < 6; j++) {
#pragma unroll
            for (int i = 0; i < 4; i++) {
                s16x4 t;
                if constexpr (B_F32)
                    t = (s16x4){f2bf(stf[j][0][i]), f2bf(stf[j][1][i]),
                                f2bf(stf[j][2][i]), f2bf(stf[j][3][i])};
                else
                    t = (s16x4){sth[j][0][i], sth[j][1][i], sth[j][2][i], sth[j][3][i]};
                *(s16x4*)&lds[(q * 4 + i) * 200 + 32 * j + goff] = t;
            }
        }
    };

    bf16x8 bv[2][6];
    auto HOIST = [&]() {                 // 12 B-frags -> regs
        const int bro = wave * 32 + row;
        const int sgr = (row >> 2) & 3;
#pragma unroll
        for (int c = 0; c < 6; c++) {
            bv[0][c] = *(const bf16x8*)&lds[bro * 200 + c * 32 + ((kgrp ^ sgr) << 3)];
            bv[1][c] = *(const bf16x8*)&lds[(bro + 16) * 200 + c * 32 + ((kgrp ^ sgr) << 3)];
        }
    };

    const int oc8  = lane >> 3;          // 0..7 (epilogue oc row)
    const int pxq8 = lane & 7;           // 0..7 (epilogue px quad)
    float* ep = &eps[wave][0];
    auto computeStore = [&](const bf16x8* a, int mi, int px0) {
        f32x4 acc0 = (f32x4){0.f, 0.f, 0.f, 0.f};
        f32x4 acc1 = (f32x4){0.f, 0.f, 0.f, 0.f};
#pragma unroll
        for (int c = 0; c < 6; c++) {
            acc0 = __builtin_amdgcn_mfma_f32_16x16x32_bf16(a[c], bv[0][c], acc0, 0, 0, 0);
            acc1 = __builtin_amdgcn_mfma_f32_16x16x32_bf16(a[c], bv[1][c], acc1, 0, 0, 0);
        }
#pragma unroll
        for (int r = 0; r < 4; r++) {
            ep[(kgrp * 4 + r) * 36 + row]      = acc0[r];
            ep[(kgrp * 4 + r) * 36 + 16 + row] = acc1[r];
        }
        // wave-internal LDS ordering (lgkmcnt) — no barrier needed.
#pragma unroll
        for (int rr = 0; rr < 2; rr++) {
            const int oc16 = oc8 + rr * 8;               // 0..15
            f32x4 vv = *reinterpret_cast<const f32x4*>(&ep[oc16 * 36 + pxq8 * 4]);
            long off = (long)b * bstrideC + (long)(mi * 16 + oc16) * HW
                     + px0 + wave * 32 + pxq8 * 4;
            if constexpr (OUT_F32) {
                __builtin_nontemporal_store(vv, reinterpret_cast<f32x4*>((float*)Cg + off));
            } else {
                *reinterpret_cast<s16x4*>((short*)Cg + off) =
                    (s16x4){f2bf(vv[0]), f2bf(vv[1]), f2bf(vv[2]), f2bf(vv[3])};
            }
        }
    };
    auto COMPUTE = [&](int px0) {        // expects aA preloaded with mi=0
        for (int mi = 0; mi < NOCT; mi += 2) {
            loadA(aB, mi + 1);
            computeStore(aA, mi, px0);
            if (mi + 2 < NOCT) loadA(aA, mi + 2);
            computeStore(aB, mi + 1, px0);
        }
    };

    // ---- slab pipeline ----
    loadA(aA, 0);
    SLOAD(pxbase);            // slab0
    SWRITE();
    __syncthreads();
    HOIST();
    __syncthreads();          // all waves past hoist -> B-LDS reusable
    SLOAD(pxbase + 128);      // slab1 loads in flight during compute0
    COMPUTE(pxbase);
    loadA(aA, 0);             // re-arm A for slab1
    SWRITE();                 // waits on slab1 loads (counted vmcnt)
    __syncthreads();
    HOIST();
    COMPUTE(pxbase + 128);
}

// ---------------------------------------------------------------------------
// depthwise 3x3 (pad 1): register-rolling rows, NO LDS image.
// ---------------------------------------------------------------------------
__global__ __launch_bounds__(256)
void dwconv_sumsq(const short* __restrict__ in, const float* __restrict__ w2,
                  short* __restrict__ outp, float* __restrict__ kss)
{
    __shared__ float red[4];
    const long bgc = blockIdx.x;           // b*384 + gc
    const int  gc  = (int)(bgc % DIM2);
    const int  b   = (int)(bgc / DIM2);
    const int  tid = threadIdx.x;
    const int  tx  = tid & 15;             // x-group: px [tx*8, tx*8+8)
    const int  ty  = tid >> 4;             // y-strip: rows [ty*8, ty*8+8)
    const int  lane = tid & 63;
    const int  x0 = tx * 8;
    const int  y0 = ty * 8;
    const short* src = in + (bgc << 14);
    short* dst = outp + (bgc << 14);

    float w[9];
#pragma unroll
    for (int i = 0; i < 9; i++) w[i] = w2[gc * 9 + i];   // wave-uniform -> SGPR

    float r0[10], r1[10], r2[10];
    auto loadRow = [&](float* r, int y) {
        if ((unsigned)y > 127u) {
#pragma unroll
            for (int i = 0; i < 10; i++) r[i] = 0.f;
            return;
        }
        bf16x8 v = *reinterpret_cast<const bf16x8*>(&src[y * 128 + x0]);
#pragma unroll
        for (int i = 0; i < 8; i++) r[i + 1] = bf2f(v[i]);
        float left  = __shfl(r[8], lane - 1);
        float right = __shfl(r[1], lane + 1);
        r[0] = (tx == 0)  ? 0.f : left;
        r[9] = (tx == 15) ? 0.f : right;
    };

    loadRow(r0, y0 - 1);
    loadRow(r1, y0);
    float ssq = 0.f;
#pragma unroll
    for (int k = 0; k < 8; k++) {
        const int yy = y0 + k;
        loadRow(r2, yy + 1);
        bf16x8 o;
#pragma unroll
        for (int j = 0; j < 8; j++) {
            float s = r0[j] * w[0] + r0[j + 1] * w[1] + r0[j + 2] * w[2]
                    + r1[j] * w[3] + r1[j + 1] * w[4] + r1[j + 2] * w[5]
                    + r2[j] * w[6] + r2[j + 1] * w[7] + r2[j + 2] * w[8];
            o[j] = f2bf(s);
            ssq += s * s;
        }
        *reinterpret_cast<bf16x8*>(&dst[yy * 128 + x0]) = o;
#pragma unroll
        for (int i = 0; i < 10; i++) { r0[i] = r1[i]; r1[i] = r2[i]; }
    }

    for (int o = 32; o; o >>= 1) ssq += __shfl_xor(ssq, o);
    if ((tid & 63) == 0) red[tid >> 6] = ssq;
    __syncthreads();
    if (gc < DIM && tid == 0)
        kss[b * DIM + gc] = red[0] + red[1] + red[2] + red[3];
}

// ---------------------------------------------------------------------------
// QK^T via MFMA over contiguous px — TWO-HEAD tiling, NSPLIT=128 for 16
// waves/CU (latency-hiding probe). One block covers a head PAIR = 48 rows
// = 3 m-tiles x 3 n-tiles; computes the 7 tile-pairs intersecting the two
// 24x24 diagonal blocks. Grid (NSPLIT, 32). Fused q sumsq.
// ---------------------------------------------------------------------------
__global__ __launch_bounds__(64)
void qk_mfma(const float* __restrict__ q, const short* __restrict__ kvb,
             float* __restrict__ part, float* __restrict__ pssq)
{
    const int split = blockIdx.x;          // 0..NSPLIT-1
    const int g     = blockIdx.y;          // b*4 + head-pair
    const int b = g >> 2, hp = g & 3;
    const int lane = threadIdx.x;
    const int row = lane & 15;
    const int kg  = (lane >> 4) * 8;
    const int CHUNK = HW / NSPLIT;         // 128

    const float* qm[3];
    const short* km[3];
#pragma unroll
    for (int t = 0; t < 3; t++) {
        qm[t] = q   + ((long)b * DIM  + hp * 48 + t * 16 + row) * HW + split * CHUNK + kg;
        km[t] = kvb + ((long)b * DIM2 + hp * 48 + t * 16 + row) * HW + split * CHUNK + kg;
    }

    // 7 needed (mt,nt) pairs
    const int MT[7] = {0,0,1,1,1,2,2};
    const int NT[7] = {0,1,0,1,2,1,2};
    f32x4 acc[7];
#pragma unroll
    for (int p = 0; p < 7; p++) acc[p] = (f32x4){0.f, 0.f, 0.f, 0.f};
    float ssq[3] = {0.f, 0.f, 0.f};

#pragma unroll
    for (int s = 0; s < CHUNK / 32; s++) {
        const int px = s * 32;
        bf16x8 a[3], bvv[3];
#pragma unroll
        for (int t = 0; t < 3; t++) {
            float4 qa = *reinterpret_cast<const float4*>(qm[t] + px);
            float4 qb = *reinterpret_cast<const float4*>(qm[t] + px + 4);
            ssq[t] += qa.x*qa.x + qa.y*qa.y + qa.z*qa.z + qa.w*qa.w
                    + qb.x*qb.x + qb.y*qb.y + qb.z*qb.z + qb.w*qb.w;
            a[t][0]=f2bf(qa.x); a[t][1]=f2bf(qa.y); a[t][2]=f2bf(qa.z); a[t][3]=f2bf(qa.w);
            a[t][4]=f2bf(qb.x); a[t][5]=f2bf(qb.y); a[t][6]=f2bf(qb.z); a[t][7]=f2bf(qb.w);
            bvv[t] = *reinterpret_cast<const bf16x8*>(km[t] + px);
        }
#pragma unroll
        for (int p = 0; p < 7; p++)
            acc[p] = __builtin_amdgcn_mfma_f32_16x16x32_bf16(a[MT[p]], bvv[NT[p]], acc[p], 0, 0, 0);
    }

    // reduce ssq across the 4 kg-groups sharing a row
#pragma unroll
    for (int t = 0; t < 3; t++) {
        ssq[t] += __shfl_xor(ssq[t], 16);
        ssq[t] += __shfl_xor(ssq[t], 32);
    }
    if (lane < 16) {
        float* ps = pssq + ((long)split * 32 + g) * 48;
#pragma unroll
        for (int t = 0; t < 3; t++) ps[t * 16 + lane] = ssq[t];
    }

    // scatter acc -> per-head 24x24 logits (same-head pairs only)
#pragma unroll
    for (int p = 0; p < 7; p++) {
#pragma unroll
        for (int r = 0; r < 4; r++) {
            const int c48 = MT[p] * 16 + (lane >> 4) * 4 + r;
            const int d48 = NT[p] * 16 + row;
            const int hc = c48 >= CD, hd = d48 >= CD;
            if (hc == hd) {
                const int bh = b * 8 + hp * 2 + hc;
                part[((long)split * 64 + bh) * 576 + (c48 - hc * CD) * CD + (d48 - hd * CD)]
                    = acc[p][r];
            }
        }
    }
}

// ---------------------------------------------------------------------------
// FUSED: softmax + buildm (M[b] = pw @ blockdiag(attn[b]), bf16, packed
// fragment order). One block per (b,h); prob lives in LDS between phases.
// ---------------------------------------------------------------------------
__global__ __launch_bounds__(256)
void softmax_buildm(const float* __restrict__ part, const float* __restrict__ pssq,
                    const float* __restrict__ kss, const float* __restrict__ scale,
                    const float* __restrict__ pw, short* __restrict__ M)
{
    __shared__ float probL[CD][CD + 1];
    __shared__ float qsL[CD];
    const int bh = blockIdx.x;             // b*8 + h
    const int b = bh >> 3, h = bh & 7;
    const int t = threadIdx.x;

    // qs[c]: sum over splits; pssq layout [split][32 g][48], g=b*4+(h>>1)
    if (t < CD) {
        const long gidx = (long)(b * 4 + (h >> 1)) * 48 + (h & 1) * CD + t;
        float qs = 0.f;
        for (int s = 0; s < NSPLIT; s++) qs += pssq[(long)s * 32 * 48 + gidx];
        qsL[t] = qs;
    }
    __syncthreads();

    const int dd = t & 31;
    const float sc = scale[h];
#pragma unroll
    for (int p = 0; p < 3; p++) {
        const int c = p * 8 + (t >> 5);
        float val = -1e30f;
        if (dd < CD) {
            float raw = 0.f;
            for (int s = 0; s < NSPLIT; s++)
                raw += part[((long)s * 64 + bh) * 576 + c * CD + dd];
            float qn = fmaxf(sqrtf(qsL[c]), 1e-12f);
            float kn = fmaxf(sqrtf(kss[b * DIM + h * CD + dd]), 1e-12f);
            val = raw * sc / (qn * kn);
        }
        float m = val;
        for (int o = 16; o; o >>= 1) m = fmaxf(m, __shfl_xor(m, o, 32));
        float e = (dd < CD) ? expf(val - m) : 0.f;
        float s = e;
        for (int o = 16; o; o >>= 1) s += __shfl_xor(s, o, 32);
        if (dd < CD) probL[c][dd] = e / s;
    }
    __syncthreads();

    // buildm for this (b,h): 576 frag-writes (12 mi x 16 row x 3 g)
    for (int w = 0; w < 3; w++) {
        const int fid = w * 256 + t;
        if (fid >= 576) break;
        const int mi   = fid / 48;
        const int r    = fid % 48;
        const int row  = r & 15;
        const int gi   = r >> 4;           // 0..2 (8-d group within head)
        const int gvc0 = h * CD + gi * 8;
        const int cf   = gvc0 >> 5;
        const int kge  = (gvc0 >> 3) & 3;
        const int l    = (kge << 4) | row;
        const int oc   = mi * 16 + row;
        bf16x8 o;
#pragma unroll
        for (int e = 0; e < 8; e++) {
            const int d = gi * 8 + e;
            float s = 0.f;
#pragma unroll
            for (int cc = 0; cc < CD; cc++)
                s += pw[oc * DIM + h * CD + cc] * probL[cc][d];
            o[e] = f2bf(s);
        }
        long idx = (long)b * 4608 + mi * 384 + cf * 64 + l;
        *reinterpret_cast<bf16x8*>(M + idx * 8) = o;
    }
}

// ---------------------------------------------------------------------------
extern "C" void kernel_launch(void* const* d_in, const int* in_sizes, int n_in,
                              void* d_out, int out_size, void* d_ws, size_t ws_size,
                              hipStream_t stream)
{
    const float* kv    = (const float*)d_in[0];
    const float* q     = (const float*)d_in[1];
    const float* w1    = (const float*)d_in[2];   // (384,192)
    const float* w2    = (const float*)d_in[3];   // (384,9)
    const float* pw    = (const float*)d_in[4];   // (192,192)
    const float* scale = (const float*)d_in[5];   // (8)
    float* out = (float*)d_out;

    char* ws = (char*)d_ws;
    long off = 0;
    auto alloc = [&](long bytes) { char* p = ws + off; off += (bytes + 255) & ~255L; return p; };
    short* kvf1 = (short*)alloc((long)NB * DIM2 * HW * 2);   // 96 MiB
    short* kvb  = (short*)alloc((long)NB * DIM2 * HW * 2);   // 96 MiB
    short* wb1  = (short*)alloc((long)DIM2 * DIM * 2);
    float* kss  = (float*)alloc((long)NB * DIM * 4);
    float* part = (float*)alloc((long)NSPLIT * 64 * 576 * 4);
    float* pssq = (float*)alloc((long)NSPLIT * 32 * 48 * 4);
    short* M    = (short*)alloc((long)NB * DIM * DIM * 2);

    // 1) w1 -> bf16, packed fragment order
    prep_w1<<<36, 256, 0, stream>>>(w1, wb1);

    // 2) 1x1 conv (GEMM): kvf1 = w1 @ kv, bf16 out  (2 slabs/block)
    gemm_k192<24, true, false, false><<<dim3(64, NB), 256, 0, stream>>>(
        wb1, kv, kvf1, (long)DIM * HW, (long)DIM2 * HW);

    // 3) depthwise 3x3 + k sumsq (register-rolling, no LDS)
    dwconv_sumsq<<<NB * DIM2, 256, 0, stream>>>(kvf1, w2, kvb, kss);

    // 4) QK^T partials + q sumsq partials (two-head MFMA tiling, NSPLIT=128)
    qk_mfma<<<dim3(NSPLIT, 32), 64, 0, stream>>>(q, kvb, part, pssq);

    // 5) fused softmax + buildm (M in packed fragment order, bf16)
    softmax_buildm<<<64, 256, 0, stream>>>(part, pssq, kss, scale, pw, M);

    // 6) out = M[b] @ v  (PV + proj fused), f32 out  (2 slabs/block)
    gemm_k192<12, false, true, true><<<dim3(64, NB), 256, 0, stream>>>(
        M, kvb + (long)DIM * HW, out, (long)DIM2 * HW, (long)DIM * HW);
}

// Round 16
// 177.279 us; speedup vs baseline: 1.1149x; 1.1149x over previous
//
#include <hip/hip_runtime.h>
#include <hip/hip_bf16.h>

#define HW 16384
#define DIM 192
#define DIM2 384
#define NB 8
#define HEADS 8
#define CD 24
#define NSPLIT 64

typedef float f32x4 __attribute__((ext_vector_type(4)));
typedef short bf16x8 __attribute__((ext_vector_type(8)));
typedef short s16x4 __attribute__((ext_vector_type(4)));

__device__ __forceinline__ short f2bf(float f) {
    __hip_bfloat16 h = __float2bfloat16(f);
    return *reinterpret_cast<short*>(&h);
}
__device__ __forceinline__ float bf2f(short s) {
    __hip_bfloat16 h = *reinterpret_cast<__hip_bfloat16*>(&s);
    return __bfloat162float(h);
}

// ---------------------------------------------------------------------------
// prep: w1 (384x192 f32) -> bf16 packed in MFMA-fragment order
// ---------------------------------------------------------------------------
__global__ __launch_bounds__(256)
void prep_w1(const float* __restrict__ w1, short* __restrict__ wb1)
{
    int idx = blockIdx.x * 256 + threadIdx.x;      // < 24*6*64 = 9216
    if (idx >= 9216) return;
    int mi = idx / 384, rem = idx % 384;
    int c = rem >> 6, l = rem & 63;
    int oc = mi * 16 + (l & 15);
    int kb = c * 32 + (l >> 4) * 8;
    const float* src = w1 + (long)oc * DIM + kb;
    float4 v0 = *reinterpret_cast<const float4*>(src);
    float4 v1 = *reinterpret_cast<const float4*>(src + 4);
    bf16x8 o;
    o[0]=f2bf(v0.x); o[1]=f2bf(v0.y); o[2]=f2bf(v0.z); o[3]=f2bf(v0.w);
    o[4]=f2bf(v1.x); o[5]=f2bf(v1.y); o[6]=f2bf(v1.z); o[7]=f2bf(v1.w);
    *reinterpret_cast<bf16x8*>(wb1 + (long)idx * 8) = o;
}

// ---------------------------------------------------------------------------
// MFMA GEMM, K=192 (r9 structure, proven best): block = TWO 128-px slabs,
// slab-level software pipeline. Full-line epilogue store segments.
// ---------------------------------------------------------------------------
template<int NOCT, bool B_F32, bool PER_BATCH_A, bool OUT_F32>
__global__ __launch_bounds__(256, 2)
void gemm_k192(const short* __restrict__ Ab, const void* __restrict__ Bg,
               void* __restrict__ Cg, long bstrideB, long bstrideC)
{
    __shared__ short lds[128 * 200];     // B slab (51.2 KB)
    __shared__ float eps[4][16 * 36];    // epilogue transpose buf (9 KB)
    const int tid  = threadIdx.x;
    const int lane = tid & 63;
    const int wave = tid >> 6;
    const int pxbase = blockIdx.x * 256; // two 128-px slabs per block
    const int b    = blockIdx.y;

    const int row  = lane & 15;
    const int kgrp = lane >> 4;          // 0..3
    const short* A0 = Ab + (PER_BATCH_A ? (long)b * NOCT * 3072 : 0);

    bf16x8 aA[6], aB[6];
    auto loadA = [&](bf16x8* dst, int mi) {
#pragma unroll
        for (int c = 0; c < 6; c++)
            dst[c] = *reinterpret_cast<const bf16x8*>(
                &A0[((long)(mi * 6 + c) * 64 + lane) * 8]);
    };

    // ---- staging: thread (q = px-quad 0..31, kl = k-lane 0..7) ----
    const int q  = tid & 31;             // px = 4q .. 4q+3
    const int kl = tid >> 5;             // k = 32j + 4kl + e
    f32x4 stf[6][4];
    s16x4 sth[6][4];
    auto SLOAD = [&](int px0) {          // issue 24 vector loads (kept in regs)
        if constexpr (B_F32) {
            const float* src = (const float*)Bg + (long)b * bstrideB + px0 + q * 4;
#pragma unroll
            for (int j = 0; j < 6; j++)
#pragma unroll
                for (int e = 0; e < 4; e++)
                    stf[j][e] = __builtin_nontemporal_load(
                        reinterpret_cast<const f32x4*>(src + (long)(32 * j + 4 * kl + e) * HW));
        } else {
            const short* src = (const short*)Bg + (long)b * bstrideB + px0 + q * 4;
#pragma unroll
            for (int j = 0; j < 6; j++)
#pragma unroll
                for (int e = 0; e < 4; e++)
                    sth[j][e] = __builtin_nontemporal_load(
                        reinterpret_cast<const s16x4*>(src + (long)(32 * j + 4 * kl + e) * HW));
        }
    };
    auto SWRITE = [&]() {                // cvt + transpose + swizzled LDS write
        const int goff = (((kl >> 1) ^ (q & 3)) << 3) + (kl & 1) * 4;
#pragma unroll
        for (int j = 0; j < 6; j++) {
#pragma unroll
            for (int i = 0; i < 4; i++) {
                s16x4 t;
                if constexpr (B_F32)
                    t = (s16x4){f2bf(stf[j][0][i]), f2bf(stf[j][1][i]),
                                f2bf(stf[j][2][i]), f2bf(stf[j][3][i])};
                else
                    t = (s16x4){sth[j][0][i], sth[j][1][i], sth[j][2][i], sth[j][3][i]};
                *(s16x4*)&lds[(q * 4 + i) * 200 + 32 * j + goff] = t;
            }
        }
    };

    bf16x8 bv[2][6];
    auto HOIST = [&]() {                 // 12 B-frags -> regs
        const int bro = wave * 32 + row;
        const int sgr = (row >> 2) & 3;
#pragma unroll
        for (int c = 0; c < 6; c++) {
            bv[0][c] = *(const bf16x8*)&lds[bro * 200 + c * 32 + ((kgrp ^ sgr) << 3)];
            bv[1][c] = *(const bf16x8*)&lds[(bro + 16) * 200 + c * 32 + ((kgrp ^ sgr) << 3)];
        }
    };

    const int oc8  = lane >> 3;          // 0..7 (epilogue oc row)
    const int pxq8 = lane & 7;           // 0..7 (epilogue px quad)
    float* ep = &eps[wave][0];
    auto computeStore = [&](const bf16x8* a, int mi, int px0) {
        f32x4 acc0 = (f32x4){0.f, 0.f, 0.f, 0.f};
        f32x4 acc1 = (f32x4){0.f, 0.f, 0.f, 0.f};
#pragma unroll
        for (int c = 0; c < 6; c++) {
            acc0 = __builtin_amdgcn_mfma_f32_16x16x32_bf16(a[c], bv[0][c], acc0, 0, 0, 0);
            acc1 = __builtin_amdgcn_mfma_f32_16x16x32_bf16(a[c], bv[1][c], acc1, 0, 0, 0);
        }
#pragma unroll
        for (int r = 0; r < 4; r++) {
            ep[(kgrp * 4 + r) * 36 + row]      = acc0[r];
            ep[(kgrp * 4 + r) * 36 + 16 + row] = acc1[r];
        }
        // wave-internal LDS ordering (lgkmcnt) — no barrier needed.
#pragma unroll
        for (int rr = 0; rr < 2; rr++) {
            const int oc16 = oc8 + rr * 8;               // 0..15
            f32x4 vv = *reinterpret_cast<const f32x4*>(&ep[oc16 * 36 + pxq8 * 4]);
            long off = (long)b * bstrideC + (long)(mi * 16 + oc16) * HW
                     + px0 + wave * 32 + pxq8 * 4;
            if constexpr (OUT_F32) {
                __builtin_nontemporal_store(vv, reinterpret_cast<f32x4*>((float*)Cg + off));
            } else {
                *reinterpret_cast<s16x4*>((short*)Cg + off) =
                    (s16x4){f2bf(vv[0]), f2bf(vv[1]), f2bf(vv[2]), f2bf(vv[3])};
            }
        }
    };
    auto COMPUTE = [&](int px0) {        // expects aA preloaded with mi=0
        for (int mi = 0; mi < NOCT; mi += 2) {
            loadA(aB, mi + 1);
            computeStore(aA, mi, px0);
            if (mi + 2 < NOCT) loadA(aA, mi + 2);
            computeStore(aB, mi + 1, px0);
        }
    };

    // ---- slab pipeline ----
    loadA(aA, 0);
    SLOAD(pxbase);            // slab0
    SWRITE();
    __syncthreads();
    HOIST();
    __syncthreads();          // all waves past hoist -> B-LDS reusable
    SLOAD(pxbase + 128);      // slab1 loads in flight during compute0
    COMPUTE(pxbase);
    loadA(aA, 0);             // re-arm A for slab1
    SWRITE();                 // waits on slab1 loads (counted vmcnt)
    __syncthreads();
    HOIST();
    COMPUTE(pxbase + 128);
}

// ---------------------------------------------------------------------------
// depthwise 3x3 (pad 1): register-rolling rows, NO LDS image.
// ---------------------------------------------------------------------------
__global__ __launch_bounds__(256)
void dwconv_sumsq(const short* __restrict__ in, const float* __restrict__ w2,
                  short* __restrict__ outp, float* __restrict__ kss)
{
    __shared__ float red[4];
    const long bgc = blockIdx.x;           // b*384 + gc
    const int  gc  = (int)(bgc % DIM2);
    const int  b   = (int)(bgc / DIM2);
    const int  tid = threadIdx.x;
    const int  tx  = tid & 15;             // x-group: px [tx*8, tx*8+8)
    const int  ty  = tid >> 4;             // y-strip: rows [ty*8, ty*8+8)
    const int  lane = tid & 63;
    const int  x0 = tx * 8;
    const int  y0 = ty * 8;
    const short* src = in + (bgc << 14);
    short* dst = outp + (bgc << 14);

    float w[9];
#pragma unroll
    for (int i = 0; i < 9; i++) w[i] = w2[gc * 9 + i];   // wave-uniform -> SGPR

    float r0[10], r1[10], r2[10];
    auto loadRow = [&](float* r, int y) {
        if ((unsigned)y > 127u) {
#pragma unroll
            for (int i = 0; i < 10; i++) r[i] = 0.f;
            return;
        }
        bf16x8 v = *reinterpret_cast<const bf16x8*>(&src[y * 128 + x0]);
#pragma unroll
        for (int i = 0; i < 8; i++) r[i + 1] = bf2f(v[i]);
        float left  = __shfl(r[8], lane - 1);
        float right = __shfl(r[1], lane + 1);
        r[0] = (tx == 0)  ? 0.f : left;
        r[9] = (tx == 15) ? 0.f : right;
    };

    loadRow(r0, y0 - 1);
    loadRow(r1, y0);
    float ssq = 0.f;
#pragma unroll
    for (int k = 0; k < 8; k++) {
        const int yy = y0 + k;
        loadRow(r2, yy + 1);
        bf16x8 o;
#pragma unroll
        for (int j = 0; j < 8; j++) {
            float s = r0[j] * w[0] + r0[j + 1] * w[1] + r0[j + 2] * w[2]
                    + r1[j] * w[3] + r1[j + 1] * w[4] + r1[j + 2] * w[5]
                    + r2[j] * w[6] + r2[j + 1] * w[7] + r2[j + 2] * w[8];
            o[j] = f2bf(s);
            ssq += s * s;
        }
        *reinterpret_cast<bf16x8*>(&dst[yy * 128 + x0]) = o;
#pragma unroll
        for (int i = 0; i < 10; i++) { r0[i] = r1[i]; r1[i] = r2[i]; }
    }

    for (int o = 32; o; o >>= 1) ssq += __shfl_xor(ssq, o);
    if ((tid & 63) == 0) red[tid >> 6] = ssq;
    __syncthreads();
    if (gc < DIM && tid == 0)
        kss[b * DIM + gc] = red[0] + red[1] + red[2] + red[3];
}

// ---------------------------------------------------------------------------
// QK^T via MFMA over contiguous px — TWO-HEAD tiling. One block covers a
// head PAIR = 48 contiguous rows = exactly 3 m-tiles x 3 n-tiles; computes
// only the 7 tile-pairs intersecting the two 24x24 diagonal blocks.
// Grid (NSPLIT, 32). Fused q sumsq.
// ---------------------------------------------------------------------------
__global__ __launch_bounds__(64)
void qk_mfma(const float* __restrict__ q, const short* __restrict__ kvb,
             float* __restrict__ part, float* __restrict__ pssq)
{
    const int split = blockIdx.x;          // 0..NSPLIT-1
    const int g     = blockIdx.y;          // b*4 + head-pair
    const int b = g >> 2, hp = g & 3;
    const int lane = threadIdx.x;
    const int row = lane & 15;
    const int kg  = (lane >> 4) * 8;
    const int CHUNK = HW / NSPLIT;         // 256

    const float* qm[3];
    const short* km[3];
#pragma unroll
    for (int t = 0; t < 3; t++) {
        qm[t] = q   + ((long)b * DIM  + hp * 48 + t * 16 + row) * HW + split * CHUNK + kg;
        km[t] = kvb + ((long)b * DIM2 + hp * 48 + t * 16 + row) * HW + split * CHUNK + kg;
    }

    // 7 needed (mt,nt) pairs
    const int MT[7] = {0,0,1,1,1,2,2};
    const int NT[7] = {0,1,0,1,2,1,2};
    f32x4 acc[7];
#pragma unroll
    for (int p = 0; p < 7; p++) acc[p] = (f32x4){0.f, 0.f, 0.f, 0.f};
    float ssq[3] = {0.f, 0.f, 0.f};

#pragma unroll
    for (int s = 0; s < CHUNK / 32; s++) {
        const int px = s * 32;
        bf16x8 a[3], bvv[3];
#pragma unroll
        for (int t = 0; t < 3; t++) {
            float4 qa = *reinterpret_cast<const float4*>(qm[t] + px);
            float4 qb = *reinterpret_cast<const float4*>(qm[t] + px + 4);
            ssq[t] += qa.x*qa.x + qa.y*qa.y + qa.z*qa.z + qa.w*qa.w
                    + qb.x*qb.x + qb.y*qb.y + qb.z*qb.z + qb.w*qb.w;
            a[t][0]=f2bf(qa.x); a[t][1]=f2bf(qa.y); a[t][2]=f2bf(qa.z); a[t][3]=f2bf(qa.w);
            a[t][4]=f2bf(qb.x); a[t][5]=f2bf(qb.y); a[t][6]=f2bf(qb.z); a[t][7]=f2bf(qb.w);
            bvv[t] = *reinterpret_cast<const bf16x8*>(km[t] + px);
        }
#pragma unroll
        for (int p = 0; p < 7; p++)
            acc[p] = __builtin_amdgcn_mfma_f32_16x16x32_bf16(a[MT[p]], bvv[NT[p]], acc[p], 0, 0, 0);
    }

    // reduce ssq across the 4 kg-groups sharing a row
#pragma unroll
    for (int t = 0; t < 3; t++) {
        ssq[t] += __shfl_xor(ssq[t], 16);
        ssq[t] += __shfl_xor(ssq[t], 32);
    }
    if (lane < 16) {
        float* ps = pssq + ((long)split * 32 + g) * 48;
#pragma unroll
        for (int t = 0; t < 3; t++) ps[t * 16 + lane] = ssq[t];
    }

    // scatter acc -> per-head 24x24 logits (same-head pairs only)
#pragma unroll
    for (int p = 0; p < 7; p++) {
#pragma unroll
        for (int r = 0; r < 4; r++) {
            const int c48 = MT[p] * 16 + (lane >> 4) * 4 + r;
            const int d48 = NT[p] * 16 + row;
            const int hc = c48 >= CD, hd = d48 >= CD;
            if (hc == hd) {
                const int bh = b * 8 + hp * 2 + hc;
                part[((long)split * 64 + bh) * 576 + (c48 - hc * CD) * CD + (d48 - hd * CD)]
                    = acc[p][r];
            }
        }
    }
}

// ---------------------------------------------------------------------------
// FUSED: softmax + buildm (M[b] = pw @ blockdiag(attn[b]), bf16, packed
// fragment order). One block per (b,h); prob lives in LDS between phases.
// ---------------------------------------------------------------------------
__global__ __launch_bounds__(256)
void softmax_buildm(const float* __restrict__ part, const float* __restrict__ pssq,
                    const float* __restrict__ kss, const float* __restrict__ scale,
                    const float* __restrict__ pw, short* __restrict__ M)
{
    __shared__ float probL[CD][CD + 1];
    __shared__ float qsL[CD];
    const int bh = blockIdx.x;             // b*8 + h
    const int b = bh >> 3, h = bh & 7;
    const int t = threadIdx.x;

    // qs[c]: sum over splits; pssq layout [split][32 g][48], g=b*4+(h>>1)
    if (t < CD) {
        const long gidx = (long)(b * 4 + (h >> 1)) * 48 + (h & 1) * CD + t;
        float qs = 0.f;
        for (int s = 0; s < NSPLIT; s++) qs += pssq[(long)s * 32 * 48 + gidx];
        qsL[t] = qs;
    }
    __syncthreads();

    const int dd = t & 31;
    const float sc = scale[h];
#pragma unroll
    for (int p = 0; p < 3; p++) {
        const int c = p * 8 + (t >> 5);
        float val = -1e30f;
        if (dd < CD) {
            float raw = 0.f;
            for (int s = 0; s < NSPLIT; s++)
                raw += part[((long)s * 64 + bh) * 576 + c * CD + dd];
            float qn = fmaxf(sqrtf(qsL[c]), 1e-12f);
            float kn = fmaxf(sqrtf(kss[b * DIM + h * CD + dd]), 1e-12f);
            val = raw * sc / (qn * kn);
        }
        float m = val;
        for (int o = 16; o; o >>= 1) m = fmaxf(m, __shfl_xor(m, o, 32));
        float e = (dd < CD) ? expf(val - m) : 0.f;
        float s = e;
        for (int o = 16; o; o >>= 1) s += __shfl_xor(s, o, 32);
        if (dd < CD) probL[c][dd] = e / s;
    }
    __syncthreads();

    // buildm for this (b,h): 576 frag-writes (12 mi x 16 row x 3 g)
    for (int w = 0; w < 3; w++) {
        const int fid = w * 256 + t;
        if (fid >= 576) break;
        const int mi   = fid / 48;
        const int r    = fid % 48;
        const int row  = r & 15;
        const int gi   = r >> 4;           // 0..2 (8-d group within head)
        const int gvc0 = h * CD + gi * 8;
        const int cf   = gvc0 >> 5;
        const int kge  = (gvc0 >> 3) & 3;
        const int l    = (kge << 4) | row;
        const int oc   = mi * 16 + row;
        bf16x8 o;
#pragma unroll
        for (int e = 0; e < 8; e++) {
            const int d = gi * 8 + e;
            float s = 0.f;
#pragma unroll
            for (int cc = 0; cc < CD; cc++)
                s += pw[oc * DIM + h * CD + cc] * probL[cc][d];
            o[e] = f2bf(s);
        }
        long idx = (long)b * 4608 + mi * 384 + cf * 64 + l;
        *reinterpret_cast<bf16x8*>(M + idx * 8) = o;
    }
}

// ---------------------------------------------------------------------------
extern "C" void kernel_launch(void* const* d_in, const int* in_sizes, int n_in,
                              void* d_out, int out_size, void* d_ws, size_t ws_size,
                              hipStream_t stream)
{
    const float* kv    = (const float*)d_in[0];
    const float* q     = (const float*)d_in[1];
    const float* w1    = (const float*)d_in[2];   // (384,192)
    const float* w2    = (const float*)d_in[3];   // (384,9)
    const float* pw    = (const float*)d_in[4];   // (192,192)
    const float* scale = (const float*)d_in[5];   // (8)
    float* out = (float*)d_out;

    char* ws = (char*)d_ws;
    long off = 0;
    auto alloc = [&](long bytes) { char* p = ws + off; off += (bytes + 255) & ~255L; return p; };
    short* kvf1 = (short*)alloc((long)NB * DIM2 * HW * 2);   // 96 MiB
    short* kvb  = (short*)alloc((long)NB * DIM2 * HW * 2);   // 96 MiB
    short* wb1  = (short*)alloc((long)DIM2 * DIM * 2);
    float* kss  = (float*)alloc((long)NB * DIM * 4);
    float* part = (float*)alloc((long)NSPLIT * 64 * 576 * 4);
    float* pssq = (float*)alloc((long)NSPLIT * 32 * 48 * 4);
    short* M    = (short*)alloc((long)NB * DIM * DIM * 2);

    // 1) w1 -> bf16, packed fragment order
    prep_w1<<<36, 256, 0, stream>>>(w1, wb1);

    // 2) 1x1 conv (GEMM): kvf1 = w1 @ kv, bf16 out  (2 slabs/block)
    gemm_k192<24, true, false, false><<<dim3(64, NB), 256, 0, stream>>>(
        wb1, kv, kvf1, (long)DIM * HW, (long)DIM2 * HW);

    // 3) depthwise 3x3 + k sumsq (register-rolling, no LDS)
    dwconv_sumsq<<<NB * DIM2, 256, 0, stream>>>(kvf1, w2, kvb, kss);

    // 4) QK^T partials + q sumsq partials (two-head MFMA tiling)
    qk_mfma<<<dim3(NSPLIT, 32), 64, 0, stream>>>(q, kvb, part, pssq);

    // 5) fused softmax + buildm (M in packed fragment order, bf16)
    softmax_buildm<<<64, 256, 0, stream>>>(part, pssq, kss, scale, pw, M);

    // 6) out = M[b] @ v  (PV + proj fused), f32 out  (2 slabs/block)
    gemm_k192<12, false, true, true><<<dim3(64, NB), 256, 0, stream>>>(
        M, kvb + (long)DIM * HW, out, (long)DIM2 * HW, (long)DIM * HW);
}